// Round 4
// baseline (1884.978 us; speedup 1.0000x reference)
//
#include <hip/hip_runtime.h>
#include <stdint.h>

typedef _Float16 half_t;
typedef _Float16 half2_t __attribute__((ext_vector_type(2)));
typedef _Float16 half8_t __attribute__((ext_vector_type(8)));

#define NN   256
#define TT   1280
#define INF  128
#define HH   256
#define MM   128
#define OUTF 64
#define HM   384

#define THREADS 512

// ---- LDS layout (bytes) ----
#define LDS_PRED    0          // half[256*256] = 131072
#define LDS_PROC    131072     // int[1280]     = 5120
#define LDS_PARENT  136192     // int[1280]     = 5120
#define LDS_FMSG    141312     // half[128]     = 256
#define LDS_V2      141568     // half[2][384]  = 1536  ([ns 256 | msg 128] x2 buffers)
#define LDS_DIAG32  143104     // float[256]    = 1024
#define SMEM_BYTES  144128

// ---- d_ws layout (bytes) ----
#define WS_PRED0    0          // half[256*256]       = 131072
#define WS_WSH      131072     // half[256*384]       = 196608
#define WS_WMH      327680     // half[128*384]       =  98304
#define WS_MSGS     425984     // half[256*1280*128]  = 83886080

__device__ __forceinline__ float dot2f(half2_t a, half2_t b, float c) {
#if __has_builtin(__builtin_amdgcn_fdot2)
  return __builtin_amdgcn_fdot2(a, b, c, false);
#else
  return c + (float)a[0] * (float)b[0] + (float)a[1] * (float)b[1];
#endif
}

// ---------------- weight prep: fp32 -> fp16 copies of Ws, Wm ----------------
__global__ __launch_bounds__(256)
void prep_kernel(const float* __restrict__ Ws, const float* __restrict__ Wm,
                 half_t* __restrict__ WsH, half_t* __restrict__ WmH)
{
  const int i = blockIdx.x * 256 + threadIdx.x;     // grid covers 147456
  if (i < HH * HM) WsH[i] = (half_t)Ws[i];
  else             WmH[i - HH * HM] = (half_t)Wm[i - HH * HM];
}

// ---------------- encoder: pred0 = x @ We.T + be  (fp16 out) ----------------
__global__ __launch_bounds__(256)
void enc_kernel(const float* __restrict__ x, const float* __restrict__ We,
                const float* __restrict__ be, half_t* __restrict__ pred0)
{
  __shared__ float xs[INF];
  const int n = blockIdx.x;
  const int hh = threadIdx.x;
  if (hh < INF) xs[hh] = x[n * INF + hh];
  __syncthreads();
  const float* w = We + hh * INF;
  float acc = be[hh];
#pragma unroll 16
  for (int k = 0; k < INF; ++k) acc += w[k] * xs[k];
  pred0[n * HH + hh] = (half_t)acc;
}

// ---------------- main persistent kernel: one run per workgroup ----------------
#define P1_CHUNK(BASE, WOFF)                                                   \
  _Pragma("unroll")                                                            \
  for (int j = 0; j < 8; ++j) {                                                \
    half8_t v = *(const half8_t*)((BASE) + j * 16);                            \
    a0 = dot2f(__builtin_shufflevector(v, v, 0, 1), w1[(WOFF) + j*4 + 0], a0); \
    a1 = dot2f(__builtin_shufflevector(v, v, 2, 3), w1[(WOFF) + j*4 + 1], a1); \
    a2 = dot2f(__builtin_shufflevector(v, v, 4, 5), w1[(WOFF) + j*4 + 2], a2); \
    a3 = dot2f(__builtin_shufflevector(v, v, 6, 7), w1[(WOFF) + j*4 + 3], a3); \
  }

__global__ __launch_bounds__(THREADS, 2)
void sim_kernel(const half_t* __restrict__ WsH, const float* __restrict__ bs,
                const half_t* __restrict__ WmH, const float* __restrict__ bm,
                const float* __restrict__ Wd, const float* __restrict__ bd,
                const float* __restrict__ fmsg,
                const int* __restrict__ proc, const int* __restrict__ parent,
                const half_t* __restrict__ pred0,
                half_t* __restrict__ msgs,
                float* __restrict__ out)
{
  extern __shared__ char smem[];
  half_t* lds_pred        = (half_t*)(smem + LDS_PRED);
  int* lds_proc           = (int*)(smem + LDS_PROC);
  int* lds_par            = (int*)(smem + LDS_PARENT);
  half_t* lds_fmsg        = (half_t*)(smem + LDS_FMSG);
  char* v2base            = smem + LDS_V2;      // half[2][384]: [ns(256)|msg(128)]
  float* lds_diag         = (float*)(smem + LDS_DIAG32);

  const int tid = threadIdx.x;
  const int run = blockIdx.x;
  const int r1 = tid >> 1, h = tid & 1;    // phase-1: row, col-half
  const int r2 = tid >> 2, q = tid & 3;    // phase-2: row, col-quarter

  // ---- weights -> registers (fp16 pairs, from pre-converted fp16 images) ----
  half2_t w1[96];
  {
    const half8_t* wr = (const half8_t*)(WsH + r1 * HM + h * 192);
#pragma unroll
    for (int j = 0; j < 24; ++j) {
      half8_t v = wr[j];
      w1[4*j+0] = __builtin_shufflevector(v, v, 0, 1);
      w1[4*j+1] = __builtin_shufflevector(v, v, 2, 3);
      w1[4*j+2] = __builtin_shufflevector(v, v, 4, 5);
      w1[4*j+3] = __builtin_shufflevector(v, v, 6, 7);
    }
  }
  half2_t w2[48];
  {
    const half8_t* wr = (const half8_t*)(WmH + r2 * HM + q * 96);
#pragma unroll
    for (int j = 0; j < 12; ++j) {
      half8_t v = wr[j];
      w2[4*j+0] = __builtin_shufflevector(v, v, 0, 1);
      w2[4*j+1] = __builtin_shufflevector(v, v, 2, 3);
      w2[4*j+2] = __builtin_shufflevector(v, v, 4, 5);
      w2[4*j+3] = __builtin_shufflevector(v, v, 6, 7);
    }
  }
  const float bsv = bs[r1];
  const float bmv = bm[r2];

  // ---- LDS init: pred0 copy, schedule, first_message ----
  {
    const uint4* s = (const uint4*)pred0;
    uint4* d = (uint4*)lds_pred;
#pragma unroll
    for (int i = 0; i < (NN * HH * 2 / 16) / THREADS; ++i)   // 16 iters
      d[tid + i * THREADS] = s[tid + i * THREADS];
  }
  {
    const int* procR = proc + run * TT;
    const int* parR  = parent + run * TT;
    for (int i = tid; i < TT; i += THREADS) {
      lds_proc[i] = procR[i];
      lds_par[i]  = parR[i];
    }
  }
  if (tid < MM) lds_fmsg[tid] = (half_t)fmsg[tid];
  __syncthreads();

  float diag_reg = (h == 0) ? (float)lds_pred[run * HH + r1] : 0.f;
  half_t* msgs_run = msgs + (size_t)run * TT * MM;

  // ---- stage msg(0) into buffer 0 ----
  {
    const int p0 = lds_par[0];
    if (tid < 16) {
      uint4 v;
      if (p0 < 0) v = *(const uint4*)((const char*)lds_fmsg + tid * 16);
      else        v = *(const uint4*)((const char*)(msgs_run + (size_t)p0 * MM) + tid * 16);
      *(uint4*)(v2base + 512 + tid * 16) = v;
    }
  }
  __syncthreads();

  uint4 pfB = make_uint4(0, 0, 0, 0);   // early prefetch (issued one iter ahead)

  // ---- main loop over 1280 steps: 2 barriers per step ----
  int b = 0;
  for (int t = 0; t < TT; ++t, b ^= 1) {
    const int node  = lds_proc[t];
    // valid[i,t] == (t==0) || parent[i,t] >= 0  (invalid steps keep parent=-1;
    // every valid step t>=1 was pushed by an earlier pop with parent>=0).
    // Reconstructing it here sidesteps the bool-array marshaling dtype entirely.
    const int vld   = (t == 0) | (lds_par[t] >= 0);
    const int parn1 = (t + 1 < TT) ? lds_par[t + 1] : -1;   // parent of step t+1
    const int parn2 = (t + 2 < TT) ? lds_par[t + 2] : -1;   // parent of step t+2

    // point A: late prefetch (parent row stored during last step, safe now)
    const bool useA = (parn1 >= 0) && (parn1 == t - 1);
    uint4 pfA;
    if (tid < 16 && useA)
      pfA = *(const uint4*)((const char*)(msgs_run + (size_t)parn1 * MM) + tid * 16);

    // ---- phase 1: ns = relu(Ws @ [pred[node] | msg] + bs) ----
    const char* predrow = (const char*)(lds_pred + node * HH);
    const char* msgb    = v2base + b * 768 + 512;
    const char* b0 = h ? predrow + 384 : predrow;
    const char* b1 = h ? msgb          : predrow + 128;
    const char* b2 = h ? msgb + 128    : predrow + 256;

    float a0 = 0.f, a1 = 0.f, a2 = 0.f, a3 = 0.f;
    P1_CHUNK(b0, 0)
    P1_CHUNK(b1, 32)
    P1_CHUNK(b2, 64)
    float acc = (a0 + a1) + (a2 + a3);
    acc += __shfl_xor(acc, 1);
    const float ns_v = fmaxf(acc + bsv, 0.f);
    if (h == 0) {
      *((half_t*)(v2base + b * 768) + r1) = (half_t)ns_v;
      if (vld && node == run) diag_reg = ns_v;   // fp32 diagonal capture
    }

    // ---- stage msg(t+1) into buffer b^1 (no reader touches b^1 this step) ----
    if (t + 1 < TT && tid < 16) {
      char* dst = v2base + (b ^ 1) * 768 + 512 + tid * 16;
      if (parn1 < 0)
        *(uint4*)dst = *(const uint4*)((const char*)lds_fmsg + tid * 16);
      else if (parn1 != t)                 // parn1==t handled by phase-2 fixup
        *(uint4*)dst = useA ? pfA : pfB;
    }

    // point B: early prefetch for msg(t+2) (rows <= t-1 are all safely stored)
    if (tid < 16 && parn2 >= 0 && parn2 < t)
      pfB = *(const uint4*)((const char*)(msgs_run + (size_t)parn2 * MM) + tid * 16);

    __syncthreads();   // ns + staged msg ready

    // ---- phase 2: nm = Wm @ [ns | msg] + bm ----
    const char* vb = v2base + b * 768 + q * 192;
    float c0 = 0.f, c1 = 0.f, c2 = 0.f, c3 = 0.f;
#pragma unroll
    for (int j = 0; j < 12; ++j) {
      half8_t v = *(const half8_t*)(vb + j * 16);
      c0 = dot2f(__builtin_shufflevector(v, v, 0, 1), w2[j*4 + 0], c0);
      c1 = dot2f(__builtin_shufflevector(v, v, 2, 3), w2[j*4 + 1], c1);
      c2 = dot2f(__builtin_shufflevector(v, v, 4, 5), w2[j*4 + 2], c2);
      c3 = dot2f(__builtin_shufflevector(v, v, 6, 7), w2[j*4 + 3], c3);
    }
    float acc2 = (c0 + c1) + (c2 + c3);
    acc2 += __shfl_xor(acc2, 1);
    acc2 += __shfl_xor(acc2, 2);

    if (q == 0) {
      const float nm = acc2 + bmv;
      const half_t nmh = vld ? (half_t)nm : (half_t)0.f;
      if (vld) msgs_run[(size_t)t * MM + r2] = nmh;
      if (parn1 == t)                         // next step consumes this message
        *((half_t*)(v2base + (b ^ 1) * 768 + 512) + r2) = nmh;
    }
    if (h == 0 && vld)
      lds_pred[node * HH + r1] = (half_t)ns_v;  // safe: phase-2 reads only v2buf
    __syncthreads();   // phase-2 reads done; buffer b free; msg(t+1) visible
  }

  // ---- epilogue: out[run] = log_softmax(Wd @ diag + bd) ----
  if (h == 0) lds_diag[r1] = diag_reg;
  __syncthreads();

  if (tid < OUTF) {
    const float* wd = Wd + tid * HH;
    float acc = bd[tid];
#pragma unroll 8
    for (int k = 0; k < HH; ++k) acc += wd[k] * lds_diag[k];
    float m = acc;
#pragma unroll
    for (int off = 32; off >= 1; off >>= 1) m = fmaxf(m, __shfl_xor(m, off));
    const float e = __expf(acc - m);
    float s = e;
#pragma unroll
    for (int off = 32; off >= 1; off >>= 1) s += __shfl_xor(s, off);
    out[run * OUTF + tid] = acc - m - logf(s);
  }
}

extern "C" void kernel_launch(void* const* d_in, const int* in_sizes, int n_in,
                              void* d_out, int out_size, void* d_ws, size_t ws_size,
                              hipStream_t stream) {
  (void)in_sizes; (void)n_in; (void)out_size; (void)ws_size;
  const float* x    = (const float*)d_in[0];
  const float* fm   = (const float*)d_in[1];
  const float* We   = (const float*)d_in[2];
  const float* be   = (const float*)d_in[3];
  const float* Ws   = (const float*)d_in[4];
  const float* bs   = (const float*)d_in[5];
  const float* Wm   = (const float*)d_in[6];
  const float* bm   = (const float*)d_in[7];
  const float* Wd   = (const float*)d_in[8];
  const float* bd   = (const float*)d_in[9];
  const int* proc   = (const int*)d_in[10];
  const int* parent = (const int*)d_in[11];
  // d_in[12] (valid) intentionally unused: reconstructed as (t==0)||parent>=0,
  // which is exact per the schedule construction and immune to bool marshaling.
  float* out = (float*)d_out;

  half_t* pred0 = (half_t*)((char*)d_ws + WS_PRED0);
  half_t* WsH   = (half_t*)((char*)d_ws + WS_WSH);
  half_t* WmH   = (half_t*)((char*)d_ws + WS_WMH);
  half_t* msgs  = (half_t*)((char*)d_ws + WS_MSGS);

  (void)hipFuncSetAttribute((const void*)sim_kernel,
                            hipFuncAttributeMaxDynamicSharedMemorySize, SMEM_BYTES);

  prep_kernel<<<dim3((HH * HM + MM * HM) / 256), dim3(256), 0, stream>>>(Ws, Wm, WsH, WmH);
  enc_kernel<<<dim3(NN), dim3(256), 0, stream>>>(x, We, be, pred0);
  sim_kernel<<<dim3(NN), dim3(THREADS), SMEM_BYTES, stream>>>(
      WsH, bs, WmH, bm, Wd, bd, fm, proc, parent, pred0, msgs, out);
}